// Round 1
// baseline (995.751 us; speedup 1.0000x reference)
//
#include <hip/hip_runtime.h>
#include <math.h>

#define B_    64
#define L_    32
#define D_    64
#define NV_   100000
#define TIN_  8
#define THID_ 128
#define LROWS_ 1856   // 64*29 loss rows
#define EROWS_ 192    // 64*3 eval rows

// workspace layout (float offsets)
#define WS_TIME_EMB 0          // 2048*64
#define WS_INPUTS   131072     // 2048*64
#define WS_XIH      262144     // 2048*64
#define WS_SEQA     393216     // 1856*64
#define WS_SEQB     512000     // 192*64
#define WS_LT       524288     // 2048
#define WS_T1       526336     // 1856
#define WS_T2       528192     // 1856
#define WS_RANK     530048     // 192 (int)
// total 530240 floats = 2.07 MB

// ---------------- kernel 1: time-MLP + embedding gather -> time_emb, inputs --
__global__ __launch_bounds__(64)
void embed_kernel(const int* __restrict__ venue, const float* __restrict__ timef,
                  const float* __restrict__ vt, const float* __restrict__ w1,
                  const float* __restrict__ b1, const float* __restrict__ w2,
                  const float* __restrict__ b2, float* __restrict__ ws)
{
    float* time_emb = ws + WS_TIME_EMB;
    float* inputs   = ws + WS_INPUTS;
    const int row = blockIdx.x;          // b*32 + l
    const int d   = threadIdx.x;
    __shared__ float hid[THID_];
    float t[TIN_];
#pragma unroll
    for (int k = 0; k < TIN_; ++k) t[k] = timef[row*TIN_ + k];
    for (int h = d; h < THID_; h += 64) {
        float s = b1[h];
#pragma unroll
        for (int k = 0; k < TIN_; ++k) s = fmaf(t[k], w1[k*THID_ + h], s);
        hid[h] = fmaxf(s, 0.f);
    }
    __syncthreads();
    float v = b2[d];
#pragma unroll 16
    for (int h = 0; h < THID_; ++h) v = fmaf(hid[h], w2[h*D_ + d], v);
    time_emb[row*D_ + d] = v;
    inputs[row*D_ + d] = vt[(size_t)venue[row]*D_ + d] + v;
}

// ---------------- kernel 2: xih = inputs @ Wih^T + bih + bhh; zero accumulators
__global__ __launch_bounds__(64)
void xih_kernel(const float* __restrict__ Wih, const float* __restrict__ bih,
                const float* __restrict__ bhh, float* __restrict__ ws)
{
    const float* inputs = ws + WS_INPUTS;
    float* xih = ws + WS_XIH;
    const int row = blockIdx.x, d = threadIdx.x;
    const int g = blockIdx.x*64 + threadIdx.x;
    if (g < (2*LROWS_ + EROWS_)) ws[WS_T1 + g] = 0.f;   // zero T1,T2,rank (contiguous)
    float acc = bih[d] + bhh[d];
    const float* xr = inputs + (size_t)row*D_;
    const float* wr = Wih + (size_t)d*D_;
#pragma unroll 16
    for (int k = 0; k < D_; ++k) acc = fmaf(xr[k], wr[k], acc);
    xih[row*D_ + d] = acc;
}

// ---------------- kernel 3: RNN, one wave per batch element ------------------
__global__ __launch_bounds__(64)
void rnn_kernel(const int* __restrict__ user, const float* __restrict__ user_table,
                const float* __restrict__ Whh, float* __restrict__ ws)
{
    const float* time_emb = ws + WS_TIME_EMB;
    const float* xih = ws + WS_XIH;
    float* seqA = ws + WS_SEQA;
    float* seqB = ws + WS_SEQB;
    const int b = blockIdx.x, d = threadIdx.x;
    __shared__ float h_lds[D_];
    float whh[D_];
#pragma unroll
    for (int k = 0; k < D_; ++k) whh[k] = Whh[d*D_ + k];
    float h = user_table[(size_t)user[b]*D_ + d];
    for (int l = 0; l < 31; ++l) {
        const float te = time_emb[(b*L_ + l)*D_ + d];
        if (l < 29) seqA[(b*29 + l)*D_ + d] = h - te;     // seq[b,l] = prev h - te
        else        seqB[(b*3 + (l-29))*D_ + d] = h - te; // seq2 rows 0,1
        h_lds[d] = h;
        __syncthreads();
        float acc = xih[(b*L_ + l)*D_ + d];
#pragma unroll
        for (int k = 0; k < D_; ++k) acc = fmaf(whh[k], h_lds[k], acc);
        __syncthreads();
        h = tanhf(acc);
    }
    seqB[(b*3 + 2)*D_ + d] = h - time_emb[(b*L_ + 31)*D_ + d]; // seq2 row 2
}

// ---------------- kernel 4: target logits l_t for all 2048 rows --------------
__global__ __launch_bounds__(256)
void lt_kernel(const int* __restrict__ venue, const float* __restrict__ vt,
               float* __restrict__ ws)
{
    const float* seqA = ws + WS_SEQA;
    const float* seqB = ws + WS_SEQB;
    float* lt = ws + WS_LT;
    const int wid = threadIdx.x >> 6, lane = threadIdx.x & 63;
    const int row = blockIdx.x*4 + wid;      // 0..2047
    const float* s; int tgt;
    if (row < LROWS_) {
        const int b = row/29, l = row - b*29;
        s = seqA + (size_t)row*D_;
        tgt = venue[b*L_ + l];
    } else {
        const int r2 = row - LROWS_;
        const int b = r2/3, j = r2 - b*3;
        s = seqB + (size_t)r2*D_;
        tgt = venue[b*L_ + 29 + j];
    }
    float v = s[lane] * vt[(size_t)tgt*D_ + lane];
#pragma unroll
    for (int m = 32; m >= 1; m >>= 1) v += __shfl_xor(v, m, 64);
    if (lane == 0) lt[row] = v;
}

// ---------------- kernel 5: fused GEMM + streaming exp moments (loss rows) ---
// grid (98 chunks, 29 row-tiles); WG: 64 rows x 1024 venues; lane: 8 rows x 8 venues
__global__ __launch_bounds__(256, 2)
void gloss_kernel(const float* __restrict__ vt, float* __restrict__ ws)
{
    const float* seqA = ws + WS_SEQA;
    float* t1acc = ws + WS_T1;
    float* t2acc = ws + WS_T2;
    __shared__ __align__(16) float s_lds[64][64];
    const int tid = threadIdx.x;
    const int rowbase = blockIdx.y * 64;
#pragma unroll
    for (int i = 0; i < 4; ++i) {
        const int idx = tid + 256*i;
        const int row = idx >> 4, kc = idx & 15;
        *(float4*)&s_lds[row][kc*4] =
            *(const float4*)(seqA + (size_t)(rowbase+row)*D_ + kc*4);
    }
    __syncthreads();
    const int rg = tid >> 5, vl = tid & 31;
    float t1[8], t2[8];
#pragma unroll
    for (int i = 0; i < 8; ++i) { t1[i] = 0.f; t2[i] = 0.f; }
    const int chunk0 = blockIdx.x * 1024;
    for (int it = 0; it < 4; ++it) {
        const int vbase = chunk0 + it*256 + vl*8;
        const float* p[8]; bool valid[8];
#pragma unroll
        for (int j = 0; j < 8; ++j) {
            const int vj = vbase + j;
            valid[j] = vj < NV_;
            p[j] = vt + (size_t)(valid[j] ? vj : 0) * D_;
        }
        float acc[8][8];
#pragma unroll
        for (int i = 0; i < 8; ++i)
#pragma unroll
            for (int j = 0; j < 8; ++j) acc[i][j] = 0.f;
#pragma unroll 4
        for (int kc = 0; kc < 16; ++kc) {
            float4 vv[8], sv[8];
#pragma unroll
            for (int j = 0; j < 8; ++j) vv[j] = *(const float4*)(p[j] + kc*4);
#pragma unroll
            for (int i = 0; i < 8; ++i) sv[i] = *(const float4*)&s_lds[rg*8+i][kc*4];
#pragma unroll
            for (int i = 0; i < 8; ++i)
#pragma unroll
                for (int j = 0; j < 8; ++j) {
                    acc[i][j] = fmaf(sv[i].x, vv[j].x, acc[i][j]);
                    acc[i][j] = fmaf(sv[i].y, vv[j].y, acc[i][j]);
                    acc[i][j] = fmaf(sv[i].z, vv[j].z, acc[i][j]);
                    acc[i][j] = fmaf(sv[i].w, vv[j].w, acc[i][j]);
                }
        }
#pragma unroll
        for (int i = 0; i < 8; ++i)
#pragma unroll
            for (int j = 0; j < 8; ++j) {
                float e = __expf(acc[i][j]);
                e = valid[j] ? e : 0.f;
                t1[i] += e;
                t2[i] = fmaf(e, e, t2[i]);
            }
    }
#pragma unroll
    for (int i = 0; i < 8; ++i) {
        float a = t1[i], c = t2[i];
#pragma unroll
        for (int m = 16; m >= 1; m >>= 1) {
            a += __shfl_xor(a, m, 64);
            c += __shfl_xor(c, m, 64);
        }
        if (vl == 0) {
            atomicAdd(&t1acc[rowbase + rg*8 + i], a);
            atomicAdd(&t2acc[rowbase + rg*8 + i], c);
        }
    }
}

// ---------------- kernel 6: fused GEMM + rank counting (eval rows) -----------
__global__ __launch_bounds__(256, 2)
void geval_kernel(const int* __restrict__ venue, const float* __restrict__ vt,
                  float* __restrict__ ws)
{
    const float* seqB = ws + WS_SEQB;
    const float* lt = ws + WS_LT;
    int* rankacc = (int*)(ws + WS_RANK);
    __shared__ __align__(16) float s_lds[64][64];
    const int tid = threadIdx.x;
    const int rowbase = blockIdx.y * 64;
#pragma unroll
    for (int i = 0; i < 4; ++i) {
        const int idx = tid + 256*i;
        const int row = idx >> 4, kc = idx & 15;
        *(float4*)&s_lds[row][kc*4] =
            *(const float4*)(seqB + (size_t)(rowbase+row)*D_ + kc*4);
    }
    __syncthreads();
    const int rg = tid >> 5, vl = tid & 31;
    float ltv[8]; int tg[8]; int cnt[8];
#pragma unroll
    for (int i = 0; i < 8; ++i) {
        const int er = rowbase + rg*8 + i;
        ltv[i] = lt[LROWS_ + er];
        const int b = er/3, j = er - b*3;
        tg[i] = venue[b*L_ + 29 + j];
        cnt[i] = 0;
    }
    const int chunk0 = blockIdx.x * 1024;
    for (int it = 0; it < 4; ++it) {
        const int vbase = chunk0 + it*256 + vl*8;
        const float* p[8]; bool valid[8];
#pragma unroll
        for (int j = 0; j < 8; ++j) {
            const int vj = vbase + j;
            valid[j] = vj < NV_;
            p[j] = vt + (size_t)(valid[j] ? vj : 0) * D_;
        }
        float acc[8][8];
#pragma unroll
        for (int i = 0; i < 8; ++i)
#pragma unroll
            for (int j = 0; j < 8; ++j) acc[i][j] = 0.f;
#pragma unroll 4
        for (int kc = 0; kc < 16; ++kc) {
            float4 vv[8], sv[8];
#pragma unroll
            for (int j = 0; j < 8; ++j) vv[j] = *(const float4*)(p[j] + kc*4);
#pragma unroll
            for (int i = 0; i < 8; ++i) sv[i] = *(const float4*)&s_lds[rg*8+i][kc*4];
#pragma unroll
            for (int i = 0; i < 8; ++i)
#pragma unroll
                for (int j = 0; j < 8; ++j) {
                    acc[i][j] = fmaf(sv[i].x, vv[j].x, acc[i][j]);
                    acc[i][j] = fmaf(sv[i].y, vv[j].y, acc[i][j]);
                    acc[i][j] = fmaf(sv[i].z, vv[j].z, acc[i][j]);
                    acc[i][j] = fmaf(sv[i].w, vv[j].w, acc[i][j]);
                }
        }
#pragma unroll
        for (int i = 0; i < 8; ++i)
#pragma unroll
            for (int j = 0; j < 8; ++j) {
                const int vid = vbase + j;
                const bool g = (vid < NV_) &&
                    (acc[i][j] > ltv[i] || (acc[i][j] == ltv[i] && vid < tg[i]));
                cnt[i] += g ? 1 : 0;
            }
    }
#pragma unroll
    for (int i = 0; i < 8; ++i) {
        int a = cnt[i];
#pragma unroll
        for (int m = 16; m >= 1; m >>= 1) a += __shfl_xor(a, m, 64);
        if (vl == 0) atomicAdd(&rankacc[rowbase + rg*8 + i], a);
    }
}

// ---------------- kernel 7: finalize loss + counts ---------------------------
__global__ __launch_bounds__(256)
void fin_kernel(float* __restrict__ ws, float* __restrict__ out)
{
    const float* t1acc = ws + WS_T1;
    const float* t2acc = ws + WS_T2;
    const float* lt = ws + WS_LT;
    const int* rankacc = (const int*)(ws + WS_RANK);
    __shared__ float red[256];
    __shared__ int cc[4];
    const int tid = threadIdx.x;
    if (tid < 4) cc[tid] = 0;
    float ls = 0.f;
    for (int r = tid; r < LROWS_; r += 256) {
        const float T1 = t1acc[r], T2 = t2acc[r];
        const float pt = __expf(lt[r]) / T1;        // softmax prob of target
        const float S2 = T2 / (T1*T1);              // sum p^2
        // logp_t = p_t - log(sum_v exp(p_v)),  sum_v exp(p_v) ~= NV+1+S2/2
        ls += pt - logf((float)NV_ + 1.0f + 0.5f*S2);
    }
    red[tid] = ls;
    __syncthreads();
    for (int s = 128; s > 0; s >>= 1) {
        if (tid < s) red[tid] += red[tid + s];
        __syncthreads();
    }
    if (tid < EROWS_) {
        const int rank = rankacc[tid];
        if (rank < 1)  atomicAdd(&cc[0], 1);
        if (rank < 5)  atomicAdd(&cc[1], 1);
        if (rank < 10) atomicAdd(&cc[2], 1);
        if (rank < 20) atomicAdd(&cc[3], 1);
    }
    __syncthreads();
    if (tid == 0) {
        out[0] = -red[0] / (float)LROWS_;
        out[1] = (float)cc[0];
        out[2] = (float)cc[1];
        out[3] = (float)cc[2];
        out[4] = (float)cc[3];
        out[5] = (float)EROWS_;
    }
}

extern "C" void kernel_launch(void* const* d_in, const int* in_sizes, int n_in,
                              void* d_out, int out_size, void* d_ws, size_t ws_size,
                              hipStream_t stream)
{
    const int*   user  = (const int*)d_in[0];
    const int*   venue = (const int*)d_in[1];
    const float* timef = (const float*)d_in[2];
    const float* vt    = (const float*)d_in[3];
    const float* ut    = (const float*)d_in[4];
    const float* w1    = (const float*)d_in[5];
    const float* b1    = (const float*)d_in[6];
    const float* w2    = (const float*)d_in[7];
    const float* b2    = (const float*)d_in[8];
    const float* Wih   = (const float*)d_in[9];
    const float* Whh   = (const float*)d_in[10];
    const float* bih   = (const float*)d_in[11];
    const float* bhh   = (const float*)d_in[12];
    float* ws  = (float*)d_ws;
    float* out = (float*)d_out;

    embed_kernel<<<2048, 64, 0, stream>>>(venue, timef, vt, w1, b1, w2, b2, ws);
    xih_kernel<<<2048, 64, 0, stream>>>(Wih, bih, bhh, ws);
    rnn_kernel<<<64, 64, 0, stream>>>(user, ut, Whh, ws);
    lt_kernel<<<512, 256, 0, stream>>>(venue, vt, ws);
    gloss_kernel<<<dim3(98, 29), 256, 0, stream>>>(vt, ws);
    geval_kernel<<<dim3(98, 3), 256, 0, stream>>>(venue, vt, ws);
    fin_kernel<<<1, 256, 0, stream>>>(ws, out);
}

// Round 2
// 424.305 us; speedup vs baseline: 2.3468x; 2.3468x over previous
//
#include <hip/hip_runtime.h>
#include <math.h>

#define B_    64
#define L_    32
#define D_    64
#define NV_   100000
#define TIN_  8
#define THID_ 128
#define LROWS_ 1856   // 64*29 loss rows
#define EROWS_ 192    // 64*3 eval rows
#define VT_TILES_ 3125      // 100000/32, exact
#define CHUNK_TILES_ 25     // tiles per block chunk; 125 chunks exact

// workspace layout (float-element offsets into ws)
#define WS_TIME_EMB 0          // 2048*64 f32
#define WS_INPUTS   131072     // 2048*64 f32
#define WS_XIH      262144     // 2048*64 f32
#define WS_SEQ      393216     // 2048*64 f32 (rows 0..1855 loss, 1856..2047 eval)
#define WS_LT       524288     // 2048 f32
#define WS_T1       526336     // 1856 f32 (zeroed by xih_kernel)
#define WS_RANK     528192     // 192 int (zeroed by xih_kernel)
#define WS_SEQH     528384     // 2048*64 ushort (bf16 hi) = 65536 f32 slots
#define WS_SEQL     593920     // 2048*64 ushort (bf16 lo)
#define WS_VTH      659456     // 100000*64 ushort (bf16 hi), 128B-aligned
#define WS_VTL      3859456    // 100000*64 ushort (bf16 lo)
// end: 7059456 f32 = 28.2 MB of ws

typedef __attribute__((ext_vector_type(8)))  short s8b;   // 8 bf16 = 4 VGPR
typedef __attribute__((ext_vector_type(16))) float f16f;  // MFMA 32x32 acc

__device__ __forceinline__ unsigned short f2bf(float x) {  // RNE fp32->bf16
    unsigned u = __float_as_uint(x);
    unsigned r = u + 0x7fffu + ((u >> 16) & 1u);
    return (unsigned short)(r >> 16);
}
__device__ __forceinline__ float bf2f(unsigned short h) {
    return __uint_as_float(((unsigned)h) << 16);
}

// ---------------- kernel 0: venue_table fp32 -> bf16 hi/lo split -------------
__global__ __launch_bounds__(256)
void vtcvt_kernel(const float* __restrict__ vt, float* __restrict__ ws)
{
    unsigned short* vh = (unsigned short*)(ws + WS_VTH);
    unsigned short* vl = (unsigned short*)(ws + WS_VTL);
    const int idx = blockIdx.x * 256 + threadIdx.x;   // 0..1599999 (float4 units)
    const float4 x = ((const float4*)vt)[idx];
    ushort4 h, l;
    h.x = f2bf(x.x); l.x = f2bf(x.x - bf2f(h.x));
    h.y = f2bf(x.y); l.y = f2bf(x.y - bf2f(h.y));
    h.z = f2bf(x.z); l.z = f2bf(x.z - bf2f(h.z));
    h.w = f2bf(x.w); l.w = f2bf(x.w - bf2f(h.w));
    *(ushort4*)(vh + idx * 4) = h;
    *(ushort4*)(vl + idx * 4) = l;
}

// ---------------- kernel 1: time-MLP + embedding gather -> time_emb, inputs --
__global__ __launch_bounds__(64)
void embed_kernel(const int* __restrict__ venue, const float* __restrict__ timef,
                  const float* __restrict__ vt, const float* __restrict__ w1,
                  const float* __restrict__ b1, const float* __restrict__ w2,
                  const float* __restrict__ b2, float* __restrict__ ws)
{
    float* time_emb = ws + WS_TIME_EMB;
    float* inputs   = ws + WS_INPUTS;
    const int row = blockIdx.x;          // b*32 + l
    const int d   = threadIdx.x;
    __shared__ float hid[THID_];
    float t[TIN_];
#pragma unroll
    for (int k = 0; k < TIN_; ++k) t[k] = timef[row*TIN_ + k];
    for (int h = d; h < THID_; h += 64) {
        float s = b1[h];
#pragma unroll
        for (int k = 0; k < TIN_; ++k) s = fmaf(t[k], w1[k*THID_ + h], s);
        hid[h] = fmaxf(s, 0.f);
    }
    __syncthreads();
    float v = b2[d];
#pragma unroll 16
    for (int h = 0; h < THID_; ++h) v = fmaf(hid[h], w2[h*D_ + d], v);
    time_emb[row*D_ + d] = v;
    inputs[row*D_ + d] = vt[(size_t)venue[row]*D_ + d] + v;
}

// ---------------- kernel 2: xih = inputs @ Wih^T + bih + bhh; zero accums ----
__global__ __launch_bounds__(64)
void xih_kernel(const float* __restrict__ Wih, const float* __restrict__ bih,
                const float* __restrict__ bhh, float* __restrict__ ws)
{
    const float* inputs = ws + WS_INPUTS;
    float* xih = ws + WS_XIH;
    const int row = blockIdx.x, d = threadIdx.x;
    const int g = blockIdx.x*64 + threadIdx.x;
    if (g < (LROWS_ + EROWS_)) ws[WS_T1 + g] = 0.f;   // zero T1 then rank (contiguous)
    float acc = bih[d] + bhh[d];
    const float* xr = inputs + (size_t)row*D_;
    const float* wr = Wih + (size_t)d*D_;
#pragma unroll 16
    for (int k = 0; k < D_; ++k) acc = fmaf(xr[k], wr[k], acc);
    xih[row*D_ + d] = acc;
}

// ---------------- kernel 3: RNN, one wave per batch element ------------------
__device__ __forceinline__ void store_seq(float* __restrict__ ws, int gr, int d, float v)
{
    (ws + WS_SEQ)[gr*D_ + d] = v;
    const unsigned short hb = f2bf(v);
    const unsigned short lb = f2bf(v - bf2f(hb));
    ((unsigned short*)(ws + WS_SEQH))[gr*D_ + d] = hb;
    ((unsigned short*)(ws + WS_SEQL))[gr*D_ + d] = lb;
}

__global__ __launch_bounds__(64)
void rnn_kernel(const int* __restrict__ user, const float* __restrict__ user_table,
                const float* __restrict__ Whh, float* __restrict__ ws)
{
    const float* time_emb = ws + WS_TIME_EMB;
    const float* xih = ws + WS_XIH;
    const int b = blockIdx.x, d = threadIdx.x;
    __shared__ float h_lds[D_];
    float whh[D_];
#pragma unroll
    for (int k = 0; k < D_; ++k) whh[k] = Whh[d*D_ + k];
    float h = user_table[(size_t)user[b]*D_ + d];
    for (int l = 0; l < 31; ++l) {
        const float te = time_emb[(b*L_ + l)*D_ + d];
        const int gr = (l < 29) ? (b*29 + l) : (LROWS_ + b*3 + (l - 29));
        store_seq(ws, gr, d, h - te);
        h_lds[d] = h;
        __syncthreads();
        float acc = xih[(b*L_ + l)*D_ + d];
#pragma unroll
        for (int k = 0; k < D_; ++k) acc = fmaf(whh[k], h_lds[k], acc);
        __syncthreads();
        h = tanhf(acc);
    }
    store_seq(ws, LROWS_ + b*3 + 2, d, h - time_emb[(b*L_ + 31)*D_ + d]);
}

// ---------------- kernel 4: target logits l_t for all 2048 rows (fp32) -------
__global__ __launch_bounds__(256)
void lt_kernel(const int* __restrict__ venue, const float* __restrict__ vt,
               float* __restrict__ ws)
{
    const float* seq = ws + WS_SEQ;
    float* lt = ws + WS_LT;
    const int wid = threadIdx.x >> 6, lane = threadIdx.x & 63;
    const int row = blockIdx.x*4 + wid;      // 0..2047
    int tgt;
    if (row < LROWS_) {
        const int b = row/29, l = row - b*29;
        tgt = venue[b*L_ + l];
    } else {
        const int r2 = row - LROWS_;
        const int b = r2/3, j = r2 - b*3;
        tgt = venue[b*L_ + 29 + j];
    }
    float v = seq[(size_t)row*D_ + lane] * vt[(size_t)tgt*D_ + lane];
#pragma unroll
    for (int m = 32; m >= 1; m >>= 1) v += __shfl_xor(v, m, 64);
    if (lane == 0) lt[row] = v;
}

// ---------------- kernel 5: bf16x3 MFMA GEMM + streaming exp-sum (loss) ------
// grid (29 row-blocks of 64, 125 venue chunks); 4 waves split the chunk's tiles.
// Per wave: 64 rows (2 x 32-row subtiles) x 32-venue tiles, K=64 (4 ksteps).
__global__ __launch_bounds__(256)
void gemm_loss_kernel(float* __restrict__ ws)
{
    const unsigned short* seq_hi = (const unsigned short*)(ws + WS_SEQH);
    const unsigned short* seq_lo = (const unsigned short*)(ws + WS_SEQL);
    const unsigned short* vt_hi  = (const unsigned short*)(ws + WS_VTH);
    const unsigned short* vt_lo  = (const unsigned short*)(ws + WS_VTL);
    float* t1acc = ws + WS_T1;
    const int lane = threadIdx.x & 63, wave = threadIdx.x >> 6;
    const int col = lane & 31, half = lane >> 5;
    const int rowbase = blockIdx.x * 64;

    s8b Ah[2][4], Al[2][4];
#pragma unroll
    for (int t = 0; t < 2; ++t) {
        const int r = rowbase + t*32 + col;
#pragma unroll
        for (int s = 0; s < 4; ++s) {
            const int off = r*64 + s*16 + half*8;
            Ah[t][s] = *(const s8b*)(seq_hi + off);
            Al[t][s] = *(const s8b*)(seq_lo + off);
        }
    }
    float t1[2][16];
#pragma unroll
    for (int t = 0; t < 2; ++t)
#pragma unroll
        for (int i = 0; i < 16; ++i) t1[t][i] = 0.f;

    const int tile0 = blockIdx.y * CHUNK_TILES_;
    s8b Bh[4], Bl[4];
    {
        const int vrow = (tile0 + wave)*32 + col;
#pragma unroll
        for (int s = 0; s < 4; ++s) {
            const int off = vrow*64 + s*16 + half*8;
            Bh[s] = *(const s8b*)(vt_hi + off);
            Bl[s] = *(const s8b*)(vt_lo + off);
        }
    }
    for (int it = wave; it < CHUNK_TILES_; it += 4) {
        const bool hasnext = (it + 4) < CHUNK_TILES_;
        const int nrow = (tile0 + it + 4)*32 + col;
        f16f acc0 = {}, acc1 = {};
#pragma unroll
        for (int s = 0; s < 4; ++s) {
            acc0 = __builtin_amdgcn_mfma_f32_32x32x16_bf16(Ah[0][s], Bh[s], acc0, 0, 0, 0);
            acc1 = __builtin_amdgcn_mfma_f32_32x32x16_bf16(Ah[1][s], Bh[s], acc1, 0, 0, 0);
            acc0 = __builtin_amdgcn_mfma_f32_32x32x16_bf16(Al[0][s], Bh[s], acc0, 0, 0, 0);
            acc1 = __builtin_amdgcn_mfma_f32_32x32x16_bf16(Al[1][s], Bh[s], acc1, 0, 0, 0);
            acc0 = __builtin_amdgcn_mfma_f32_32x32x16_bf16(Ah[0][s], Bl[s], acc0, 0, 0, 0);
            acc1 = __builtin_amdgcn_mfma_f32_32x32x16_bf16(Ah[1][s], Bl[s], acc1, 0, 0, 0);
            if (hasnext) {   // B[s] dead after the mfmas above: prefetch next tile
                const int off = nrow*64 + s*16 + half*8;
                Bh[s] = *(const s8b*)(vt_hi + off);
                Bl[s] = *(const s8b*)(vt_lo + off);
            }
        }
#pragma unroll
        for (int i = 0; i < 16; ++i) {
            t1[0][i] += __expf(acc0[i]);
            t1[1][i] += __expf(acc1[i]);
        }
    }
    // reduce across the 32 lanes sharing each row set, then one atomic per row
#pragma unroll
    for (int t = 0; t < 2; ++t)
#pragma unroll
        for (int i = 0; i < 16; ++i) {
            float v = t1[t][i];
#pragma unroll
            for (int m = 1; m <= 16; m <<= 1) v += __shfl_xor(v, m, 64);
            t1[t][i] = v;
        }
    if (col == 0) {
#pragma unroll
        for (int t = 0; t < 2; ++t)
#pragma unroll
            for (int i = 0; i < 16; ++i) {
                const int r = rowbase + t*32 + (i & 3) + 8*(i >> 2) + 4*half;
                atomicAdd(&t1acc[r], t1[t][i]);
            }
    }
}

// ---------------- kernel 6: bf16x3 MFMA GEMM + rank counting (eval) ----------
// grid (6 row-blocks of 32, 125 venue chunks); 4 waves split the chunk's tiles.
__global__ __launch_bounds__(256)
void gemm_eval_kernel(const int* __restrict__ venue, float* __restrict__ ws)
{
    const unsigned short* seq_hi = (const unsigned short*)(ws + WS_SEQH);
    const unsigned short* seq_lo = (const unsigned short*)(ws + WS_SEQL);
    const unsigned short* vt_hi  = (const unsigned short*)(ws + WS_VTH);
    const unsigned short* vt_lo  = (const unsigned short*)(ws + WS_VTL);
    const float* lt = ws + WS_LT;
    int* rankacc = (int*)(ws + WS_RANK);
    const int lane = threadIdx.x & 63, wave = threadIdx.x >> 6;
    const int col = lane & 31, half = lane >> 5;
    const int rowbase = blockIdx.x * 32;     // eval-local 0..160

    s8b Ah[4], Al[4];
    {
        const int r = LROWS_ + rowbase + col;
#pragma unroll
        for (int s = 0; s < 4; ++s) {
            const int off = r*64 + s*16 + half*8;
            Ah[s] = *(const s8b*)(seq_hi + off);
            Al[s] = *(const s8b*)(seq_lo + off);
        }
    }
    float ltv[16]; int tg[16]; int cnt[16];
#pragma unroll
    for (int i = 0; i < 16; ++i) {
        const int er = rowbase + (i & 3) + 8*(i >> 2) + 4*half;  // 0..191
        ltv[i] = lt[LROWS_ + er];
        const int b = er/3, j = er - b*3;
        tg[i] = venue[b*L_ + 29 + j];
        cnt[i] = 0;
    }
    const int tile0 = blockIdx.y * CHUNK_TILES_;
    s8b Bh[4], Bl[4];
    {
        const int vrow = (tile0 + wave)*32 + col;
#pragma unroll
        for (int s = 0; s < 4; ++s) {
            const int off = vrow*64 + s*16 + half*8;
            Bh[s] = *(const s8b*)(vt_hi + off);
            Bl[s] = *(const s8b*)(vt_lo + off);
        }
    }
    for (int it = wave; it < CHUNK_TILES_; it += 4) {
        const bool hasnext = (it + 4) < CHUNK_TILES_;
        const int nrow = (tile0 + it + 4)*32 + col;
        const int vid = (tile0 + it)*32 + col;
        f16f acc = {};
#pragma unroll
        for (int s = 0; s < 4; ++s) {
            acc = __builtin_amdgcn_mfma_f32_32x32x16_bf16(Ah[s], Bh[s], acc, 0, 0, 0);
            acc = __builtin_amdgcn_mfma_f32_32x32x16_bf16(Al[s], Bh[s], acc, 0, 0, 0);
            acc = __builtin_amdgcn_mfma_f32_32x32x16_bf16(Ah[s], Bl[s], acc, 0, 0, 0);
            if (hasnext) {
                const int off = nrow*64 + s*16 + half*8;
                Bh[s] = *(const s8b*)(vt_hi + off);
                Bl[s] = *(const s8b*)(vt_lo + off);
            }
        }
#pragma unroll
        for (int i = 0; i < 16; ++i) {
            const float l = acc[i];
            const bool g = (vid != tg[i]) &&
                (l > ltv[i] || (l == ltv[i] && vid < tg[i]));
            cnt[i] += g ? 1 : 0;
        }
    }
#pragma unroll
    for (int i = 0; i < 16; ++i) {
        int v = cnt[i];
#pragma unroll
        for (int m = 1; m <= 16; m <<= 1) v += __shfl_xor(v, m, 64);
        cnt[i] = v;
    }
    if (col == 0) {
#pragma unroll
        for (int i = 0; i < 16; ++i) {
            const int er = rowbase + (i & 3) + 8*(i >> 2) + 4*half;
            atomicAdd(&rankacc[er], cnt[i]);
        }
    }
}

// ---------------- kernel 7: finalize loss + counts ---------------------------
__global__ __launch_bounds__(256)
void fin_kernel(float* __restrict__ ws, float* __restrict__ out)
{
    const float* t1acc = ws + WS_T1;
    const float* lt = ws + WS_LT;
    const int* rankacc = (const int*)(ws + WS_RANK);
    __shared__ float red[256];
    __shared__ int cc[4];
    const int tid = threadIdx.x;
    if (tid < 4) cc[tid] = 0;
    float ls = 0.f;
    for (int r = tid; r < LROWS_; r += 256)
        ls += __expf(lt[r]) / t1acc[r];          // p_t per loss row
    red[tid] = ls;
    __syncthreads();
    for (int s = 128; s > 0; s >>= 1) {
        if (tid < s) red[tid] += red[tid + s];
        __syncthreads();
    }
    if (tid < EROWS_) {
        const int rank = rankacc[tid];
        if (rank < 1)  atomicAdd(&cc[0], 1);
        if (rank < 5)  atomicAdd(&cc[1], 1);
        if (rank < 10) atomicAdd(&cc[2], 1);
        if (rank < 20) atomicAdd(&cc[3], 1);
    }
    __syncthreads();
    if (tid == 0) {
        // loss = mean(log(sum_v e^{p_v})) - mean(p_t); sum_v e^{p_v} ~= NV+1
        out[0] = logf((float)NV_ + 1.0f) - red[0] / (float)LROWS_;
        out[1] = (float)cc[0];
        out[2] = (float)cc[1];
        out[3] = (float)cc[2];
        out[4] = (float)cc[3];
        out[5] = (float)EROWS_;
    }
}

extern "C" void kernel_launch(void* const* d_in, const int* in_sizes, int n_in,
                              void* d_out, int out_size, void* d_ws, size_t ws_size,
                              hipStream_t stream)
{
    const int*   user  = (const int*)d_in[0];
    const int*   venue = (const int*)d_in[1];
    const float* timef = (const float*)d_in[2];
    const float* vt    = (const float*)d_in[3];
    const float* ut    = (const float*)d_in[4];
    const float* w1    = (const float*)d_in[5];
    const float* b1    = (const float*)d_in[6];
    const float* w2    = (const float*)d_in[7];
    const float* b2    = (const float*)d_in[8];
    const float* Wih   = (const float*)d_in[9];
    const float* Whh   = (const float*)d_in[10];
    const float* bih   = (const float*)d_in[11];
    const float* bhh   = (const float*)d_in[12];
    float* ws  = (float*)d_ws;
    float* out = (float*)d_out;

    vtcvt_kernel<<<6250, 256, 0, stream>>>(vt, ws);                 // 6.4e6 / 1024
    embed_kernel<<<2048, 64, 0, stream>>>(venue, timef, vt, w1, b1, w2, b2, ws);
    xih_kernel<<<2048, 64, 0, stream>>>(Wih, bih, bhh, ws);
    rnn_kernel<<<64, 64, 0, stream>>>(user, ut, Whh, ws);
    lt_kernel<<<512, 256, 0, stream>>>(venue, vt, ws);
    gemm_loss_kernel<<<dim3(29, 125), 256, 0, stream>>>(ws);
    gemm_eval_kernel<<<dim3(6, 125), 256, 0, stream>>>(venue, ws);
    fin_kernel<<<1, 256, 0, stream>>>(ws, out);
}